// Round 5
// baseline (1110.977 us; speedup 1.0000x reference)
//
#include <hip/hip_runtime.h>
#include <hip/hip_bf16.h>

typedef unsigned short u16;
typedef __attribute__((ext_vector_type(8))) __bf16 bf16x8;
typedef __attribute__((ext_vector_type(4))) float floatx4;

__device__ __forceinline__ u16 f2bf(float f){
  union { float f; unsigned u; } v; v.f = f;
  unsigned u = v.u;
  return (u16)((u + 0x7fffu + ((u >> 16) & 1u)) >> 16);
}

__device__ __forceinline__ floatx4 mfma16(bf16x8 a, bf16x8 b, floatx4 c){
  return __builtin_amdgcn_mfma_f32_16x16x32_bf16(a, b, c, 0, 0, 0);
}

// async global->LDS, 16B per lane. LDS dest = wave-uniform base + lane*16.
__device__ __forceinline__ void gl16(const u16* g, u16* l){
  __builtin_amdgcn_global_load_lds((const __attribute__((address_space(1))) unsigned int*)g,
                                   (__attribute__((address_space(3))) unsigned int*)l, 16, 0, 0);
}

// ------------------------------ fused transpose-cast: all 7 weights in one launch ------------------------------
__global__ __launch_bounds__(256) void tcast_all(
    const float* __restrict__ wq, const float* __restrict__ wk,
    const float* __restrict__ wv, const float* __restrict__ wo,
    const float* __restrict__ w1e, const float* __restrict__ w3e, const float* __restrict__ w2e,
    u16* __restrict__ wqkv_t, u16* __restrict__ wo_t,
    u16* __restrict__ w1t, u16* __restrict__ w3t, u16* __restrict__ w2t){
  int bid = blockIdx.x;
  const float* src; u16* dst; int R, C, nbx;
  if (bid < 256)        { src=wq;  dst=wqkv_t;          R=1024; C=1024; nbx=16; }
  else if (bid < 320)   { src=wk;  dst=wqkv_t+1048576;  R=1024; C=256;  nbx=4;  bid-=256; }
  else if (bid < 384)   { src=wv;  dst=wqkv_t+1310720;  R=1024; C=256;  nbx=4;  bid-=320; }
  else if (bid < 640)   { src=wo;  dst=wo_t;            R=1024; C=1024; nbx=16; bid-=384; }
  else if (bid < 6272)  { src=w1e; dst=w1t;             R=1024; C=2816; nbx=44; bid-=640; }
  else if (bid < 11904) { src=w3e; dst=w3t;             R=1024; C=2816; nbx=44; bid-=6272; }
  else                  { src=w2e; dst=w2t;             R=2816; C=1024; nbx=16; bid-=11904; }
  const int per = nbx * (R>>6);
  const int z = bid / per; int rem = bid - z*per;
  const int by = rem / nbx, bx = rem - by*nbx;
  src += (size_t)z * R * C;
  dst += (size_t)z * R * C;
  __shared__ u16 tile[64][65];
  const int r0 = by*64, c0 = bx*64;
  const int t = threadIdx.x;
  const int tr = t>>4, tc = (t&15)*4;
  #pragma unroll
  for (int i=0;i<4;++i){
    float4 v = *(const float4*)(src + (size_t)(r0+tr+i*16)*C + c0 + tc);
    tile[tr+i*16][tc]   = f2bf(v.x);
    tile[tr+i*16][tc+1] = f2bf(v.y);
    tile[tr+i*16][tc+2] = f2bf(v.z);
    tile[tr+i*16][tc+3] = f2bf(v.w);
  }
  __syncthreads();
  const int on = t>>3, ok = (t&7)*8;
  #pragma unroll
  for (int p=0;p<2;++p){
    int n = on + p*32;
    ushort u[8];
    #pragma unroll
    for (int j=0;j<8;++j) u[j] = tile[ok+j][n];
    *(uint4*)(dst + (size_t)(c0+n)*R + r0 + ok) = *(uint4*)u;
  }
}

// ------------------------------ elementwise ------------------------------
__global__ __launch_bounds__(256) void rmsnorm_k(const float* __restrict__ x, const float* __restrict__ w,
                                                 u16* __restrict__ ob){
  const int row = blockIdx.x, t = threadIdx.x;
  float4 v = ((const float4*)(x + (size_t)row*1024))[t];
  float ss = v.x*v.x + v.y*v.y + v.z*v.z + v.w*v.w;
  #pragma unroll
  for (int o=32;o>0;o>>=1) ss += __shfl_down(ss, o);
  __shared__ float red[4];
  if ((t&63)==0) red[t>>6]=ss;
  __syncthreads();
  float sc = rsqrtf((red[0]+red[1]+red[2]+red[3])*(1.0f/1024.0f) + 1e-5f);
  float4 wv = ((const float4*)w)[t];
  ushort4 q; q.x=f2bf(v.x*sc*wv.x); q.y=f2bf(v.y*sc*wv.y); q.z=f2bf(v.z*sc*wv.z); q.w=f2bf(v.w*sc*wv.w);
  ((ushort4*)(ob + (size_t)row*1024))[t] = q;
}

// fused: rope(q) | rope(k) | cast(v), plus pcnt zero-init.
__global__ __launch_bounds__(256) void rope_vcast_k(const float* __restrict__ qkv,
      u16* __restrict__ q_b, u16* __restrict__ k_b, u16* __restrict__ v_b,
      const float* __restrict__ cosb, const float* __restrict__ sinb, int* __restrict__ pcnt){
  int gid = blockIdx.x*256 + threadIdx.x;
  if (gid < 8) pcnt[gid] = 0;
  if (gid < 2097152){
    int idx = gid;
    int i = idx & 31, rest = idx >> 5;
    int h = rest & 15, bs = rest >> 4;
    int s = bs & 1023;
    const float* sp = qkv + (size_t)bs*1536 + h*64 + 2*i;
    float a = sp[0], b = sp[1];
    float c = cosb[s*32+i], sn = sinb[s*32+i];
    size_t p = (((size_t)bs*16) + h)*64 + 2*i;
    q_b[p]   = f2bf(a*c - b*sn);
    q_b[p+1] = f2bf(a*sn + b*c);
  } else if (gid < 2621440){
    int idx = gid - 2097152;
    int i = idx & 31, rest = idx >> 5;
    int h = rest & 3, bs = rest >> 2;
    int s = bs & 1023;
    const float* sp = qkv + (size_t)bs*1536 + 1024 + h*64 + 2*i;
    float a = sp[0], b = sp[1];
    float c = cosb[s*32+i], sn = sinb[s*32+i];
    size_t p = (((size_t)bs*4) + h)*64 + 2*i;
    k_b[p]   = f2bf(a*c - b*sn);
    k_b[p+1] = f2bf(a*sn + b*c);
  } else {
    int idx = gid - 2621440;  // < 131072
    int row = idx >> 5, c8 = (idx & 31)*8;
    const float* s = qkv + (size_t)row*1536 + 1280 + c8;
    float4 v0 = *(const float4*)s, v1 = *(const float4*)(s+4);
    ushort u[8] = {f2bf(v0.x),f2bf(v0.y),f2bf(v0.z),f2bf(v0.w),f2bf(v1.x),f2bf(v1.y),f2bf(v1.z),f2bf(v1.w)};
    *(uint4*)(v_b + (size_t)row*256 + c8) = *(uint4*)u;
  }
}

__global__ __launch_bounds__(256) void final_add(const float* __restrict__ h, const float* __restrict__ s0,
                                                 const float* __restrict__ s1, float* __restrict__ out, int n4){
  int i = blockIdx.x*256 + threadIdx.x;
  if (i >= n4) return;
  float4 a = ((const float4*)h)[i], b = ((const float4*)s0)[i], c = ((const float4*)s1)[i];
  float4 o; o.x=a.x+b.x+c.x; o.y=a.y+b.y+c.y; o.z=a.z+b.z+c.z; o.w=a.w+b.w+c.w;
  ((float4*)out)[i] = o;
}

// ------------------------------ m97-style 128x128 GEMM (qkv / wo projections) ------------------------------
template<int EPI>
__global__ __launch_bounds__(256) void gemm128(const u16* __restrict__ A, const u16* __restrict__ Bt,
                                               int M, int N, int K,
                                               float* __restrict__ Cf, const float* __restrict__ resid){
  __shared__ u16 As[128*32];
  __shared__ u16 Bs[128*32];
  const int t = threadIdx.x;
  const int wave = t>>6, lane = t&63, lrow = lane&15, quad = lane>>4;
  const int wm = (wave&1)*64, wn = (wave>>1)*64;
  const int mbase = blockIdx.y*128, nbase = blockIdx.x*128;
  const int ca = wave*128 + lane;
  const int r0 = ca>>2;
  const int jsw = (ca&3) ^ ((r0 + (r0>>2))&3);
  const u16* a0 = A  + (size_t)(mbase + r0)*K + jsw*8;
  const u16* a1 = a0 + (size_t)16*K;
  const u16* b0 = Bt + (size_t)(nbase + r0)*K + jsw*8;
  const u16* b1 = b0 + (size_t)16*K;
  u16* lA = As + wave*1024;
  u16* lB = Bs + wave*1024;
  const int swz = (lrow + (lrow>>2)) & 3;
  floatx4 acc[4][4];
  #pragma unroll
  for (int i=0;i<4;++i)
  #pragma unroll
  for (int j=0;j<4;++j) acc[i][j] = floatx4{0.f,0.f,0.f,0.f};
  for (int k0=0;k0<K;k0+=32){
    __syncthreads();
    gl16(a0, lA); gl16(a1, lA+512);
    gl16(b0, lB); gl16(b1, lB+512);
    a0 += 32; a1 += 32; b0 += 32; b1 += 32;
    __syncthreads();
    bf16x8 af[4], bfr[4];
    #pragma unroll
    for (int mi=0;mi<4;++mi) af[mi]  = *(const bf16x8*)&As[(((wm+mi*16+lrow)<<2) + (quad^swz))*8];
    #pragma unroll
    for (int ni=0;ni<4;++ni) bfr[ni] = *(const bf16x8*)&Bs[(((wn+ni*16+lrow)<<2) + (quad^swz))*8];
    #pragma unroll
    for (int mi=0;mi<4;++mi)
    #pragma unroll
    for (int ni=0;ni<4;++ni) acc[mi][ni] = mfma16(af[mi], bfr[ni], acc[mi][ni]);
  }
  #pragma unroll
  for (int mi=0;mi<4;++mi)
  #pragma unroll
  for (int ni=0;ni<4;++ni)
  #pragma unroll
  for (int i=0;i<4;++i){
    int row = mbase + wm + mi*16 + quad*4 + i;
    int col = nbase + wn + ni*16 + lrow;
    float val = acc[mi][ni][i];
    if (EPI==1) val += resid[(size_t)row*N + col];
    Cf[(size_t)row*N + col] = val;
  }
}

// ------------------------------ flash attention, paired q-tiles ------------------------------
#define ATS 72

__device__ __forceinline__ void qk_softmax(int kt, int qt, const u16* Qs, const u16* Ks, u16* Ps,
                                           floatx4* out, float* m_i, float* l_i,
                                           int wv, int lrow, int quad){
  const float NEG_INF = -__builtin_inff();
  floatx4 sc[4];
  #pragma unroll
  for (int i=0;i<4;++i) sc[i] = floatx4{0.f,0.f,0.f,0.f};
  #pragma unroll
  for (int ks=0; ks<2; ++ks){
    bf16x8 af = *(const bf16x8*)&Qs[(wv*16+lrow)*ATS + ks*32 + quad*8];
    #pragma unroll
    for (int nt=0;nt<4;++nt){
      bf16x8 bf = *(const bf16x8*)&Ks[(nt*16+lrow)*ATS + ks*32 + quad*8];
      sc[nt] = mfma16(af, bf, sc[nt]);
    }
  }
  const bool diag = (kt==qt);
  float rmax[4] = {NEG_INF,NEG_INF,NEG_INF,NEG_INF};
  #pragma unroll
  for (int nt=0;nt<4;++nt)
  #pragma unroll
  for (int i=0;i<4;++i){
    float s = sc[nt][i]*0.125f;
    if (diag && (nt*16+lrow > wv*16 + quad*4 + i)) s = NEG_INF;
    sc[nt][i] = s;
    rmax[i] = fmaxf(rmax[i], s);
  }
  #pragma unroll
  for (int o=1;o<16;o<<=1)
    #pragma unroll
    for (int i=0;i<4;++i) rmax[i] = fmaxf(rmax[i], __shfl_xor(rmax[i], o));
  float al[4], psum[4] = {0.f,0.f,0.f,0.f};
  #pragma unroll
  for (int i=0;i<4;++i){
    float mn = fmaxf(m_i[i], rmax[i]);
    al[i] = expf(m_i[i]-mn);
    m_i[i] = mn;
  }
  #pragma unroll
  for (int nt=0;nt<4;++nt)
  #pragma unroll
  for (int i=0;i<4;++i){
    float p = expf(sc[nt][i]-m_i[i]);
    sc[nt][i] = p;
    psum[i] += p;
  }
  #pragma unroll
  for (int o=1;o<16;o<<=1)
    #pragma unroll
    for (int i=0;i<4;++i) psum[i] += __shfl_xor(psum[i], o);
  #pragma unroll
  for (int i=0;i<4;++i) l_i[i] = l_i[i]*al[i] + psum[i];
  #pragma unroll
  for (int nt=0;nt<4;++nt)
    #pragma unroll
    for (int i=0;i<4;++i) out[nt][i] *= al[i];
  u16* Pw = Ps + wv*16*ATS;
  #pragma unroll
  for (int nt=0;nt<4;++nt)
  #pragma unroll
  for (int i=0;i<4;++i)
    Pw[(quad*4+i)*ATS + nt*16 + lrow] = f2bf(sc[nt][i]);
}

__device__ __forceinline__ void pv_acc(const u16* Ps, const u16* Vt, floatx4* out,
                                       int wv, int lrow, int quad){
  const u16* Pw = Ps + wv*16*ATS;
  #pragma unroll
  for (int ks=0; ks<2; ++ks){
    bf16x8 af = *(const bf16x8*)&Pw[lrow*ATS + ks*32 + quad*8];
    #pragma unroll
    for (int nt=0;nt<4;++nt){
      bf16x8 bf = *(const bf16x8*)&Vt[(nt*16+lrow)*ATS + ks*32 + quad*8];
      out[nt] = mfma16(af, bf, out[nt]);
    }
  }
}

__global__ __launch_bounds__(256) void attn2_k(const u16* __restrict__ qb, const u16* __restrict__ kb,
                                               const u16* __restrict__ vb, u16* __restrict__ ob){
  const int bx = blockIdx.x, h = blockIdx.y, b = blockIdx.z;
  const int qtA = bx, qtB = 15 - bx;
  const int kvh = h >> 2;
  __shared__ u16 QsA[64*ATS], QsB[64*ATS], Ks[64*ATS], Vt[64*ATS], PsA[64*ATS], PsB[64*ATS];
  const int t = threadIdx.x;
  const int wv = t>>6, lane = t&63, lrow = lane&15, quad = lane>>4;
  const float NEG_INF = -__builtin_inff();
  {
    const int r = t>>2, c0 = (t&3)*16;
    const u16* sA = qb + ((((size_t)(b*1024 + qtA*64 + r))*16) + h)*64 + c0;
    *(uint4*)(&QsA[r*ATS + c0])     = *(const uint4*)(sA);
    *(uint4*)(&QsA[r*ATS + c0 + 8]) = *(const uint4*)(sA + 8);
    const u16* sB = qb + ((((size_t)(b*1024 + qtB*64 + r))*16) + h)*64 + c0;
    *(uint4*)(&QsB[r*ATS + c0])     = *(const uint4*)(sB);
    *(uint4*)(&QsB[r*ATS + c0 + 8]) = *(const uint4*)(sB + 8);
  }
  floatx4 outA[4], outB[4];
  float mA[4], lA[4], mB[4], lB[4];
  #pragma unroll
  for (int i=0;i<4;++i){
    outA[i] = floatx4{0.f,0.f,0.f,0.f}; outB[i] = floatx4{0.f,0.f,0.f,0.f};
    mA[i]=NEG_INF; lA[i]=0.f; mB[i]=NEG_INF; lB[i]=0.f;
  }
  for (int kt=0; kt<=qtB; ++kt){
    const int k0 = kt*64;
    __syncthreads();
    {
      const int r = t>>2, c0 = (t&3)*16;
      const u16* src = kb + ((((size_t)(b*1024 + k0 + r))*4) + kvh)*64 + c0;
      *(uint4*)(&Ks[r*ATS + c0])     = *(const uint4*)(src);
      *(uint4*)(&Ks[r*ATS + c0 + 8]) = *(const uint4*)(src + 8);
    }
    {
      const int r = t>>3, m = t&7, c0 = m*8;
      #pragma unroll
      for (int half=0; half<2; ++half){
        int rr = r + half*32;
        uint4 v = *(const uint4*)(vb + ((((size_t)(b*1024 + k0 + rr))*4) + kvh)*64 + c0);
        const u16* s = (const u16*)&v;
        #pragma unroll
        for (int j=0;j<8;++j){
          int jj = (j + m) & 7;
          Vt[(c0+jj)*ATS + rr] = s[jj];
        }
      }
    }
    __syncthreads();
    const bool doA = (kt <= qtA);
    if (doA) qk_softmax(kt, qtA, QsA, Ks, PsA, outA, mA, lA, wv, lrow, quad);
    qk_softmax(kt, qtB, QsB, Ks, PsB, outB, mB, lB, wv, lrow, quad);
    __syncthreads();
    if (doA) pv_acc(PsA, Vt, outA, wv, lrow, quad);
    pv_acc(PsB, Vt, outB, wv, lrow, quad);
  }
  #pragma unroll
  for (int nt=0;nt<4;++nt)
  #pragma unroll
  for (int i=0;i<4;++i){
    int rA = qtA*64 + wv*16 + quad*4 + i;
    int rB = qtB*64 + wv*16 + quad*4 + i;
    ob[((size_t)(b*1024 + rA))*1024 + h*64 + nt*16 + lrow] = f2bf(outA[nt][i] / lA[i]);
    ob[((size_t)(b*1024 + rB))*1024 + h*64 + nt*16 + lrow] = f2bf(outB[nt][i] / lB[i]);
  }
}

// ------------------------------ MoE routing (128-row tiles) ------------------------------
__global__ __launch_bounds__(256) void gate_top2(const float* __restrict__ h, const float* __restrict__ fnw,
                                                 const float* __restrict__ gw,
                                                 int2* __restrict__ tidx, float2* __restrict__ tw,
                                                 int* __restrict__ counts){
  const int token = blockIdx.x*4 + (threadIdx.x>>6);
  const int lane = threadIdx.x & 63;
  const float* xr = h + (size_t)token*1024;
  float ss = 0.f;
  float acc[8] = {0,0,0,0,0,0,0,0};
  for (int it=0; it<16; ++it){
    int d = lane + it*64;
    float xv = xr[d];
    ss += xv*xv;
    float xw = xv * fnw[d];
    const float4* g4 = (const float4*)(gw + d*8);
    float4 g0 = g4[0], g1 = g4[1];
    acc[0] += xw*g0.x; acc[1] += xw*g0.y; acc[2] += xw*g0.z; acc[3] += xw*g0.w;
    acc[4] += xw*g1.x; acc[5] += xw*g1.y; acc[6] += xw*g1.z; acc[7] += xw*g1.w;
  }
  #pragma unroll
  for (int o=1;o<64;o<<=1){
    ss += __shfl_xor(ss, o);
    #pragma unroll
    for (int e=0;e<8;++e) acc[e] += __shfl_xor(acc[e], o);
  }
  if (lane==0){
    int i0=0; float v0=acc[0];
    #pragma unroll
    for (int e=1;e<8;++e) if (acc[e] > v0){ v0=acc[e]; i0=e; }
    int i1=-1; float v1=-__builtin_inff();
    #pragma unroll
    for (int e=0;e<8;++e) if (e!=i0 && acc[e] > v1){ v1=acc[e]; i1=e; }
    float scl = rsqrtf(ss*(1.0f/1024.0f) + 1e-5f);
    float e2 = expf((v1 - v0)*scl);
    float w0 = 1.0f/(1.0f+e2);
    float w1 = e2/(1.0f+e2);
    int2 ii; ii.x=i0; ii.y=i1; tidx[token]=ii;
    float2 ww; ww.x=w0; ww.y=w1; tw[token]=ww;
    atomicAdd(&counts[i0],1);
    atomicAdd(&counts[i1],1);
  }
}

__global__ void offsets_k(const int* __restrict__ counts, int* __restrict__ poff, int* __restrict__ pcur,
                          int* __restrict__ tileinfo, int* __restrict__ ntiles){
  if (threadIdx.x==0){
    int run=0, nt=0;
    for (int e=0;e<8;++e){
      poff[e]=run; pcur[e]=run;
      int c = counts[e];
      int tl = (c+127)>>7;
      for (int mt=0; mt<tl; ++mt) tileinfo[nt++] = (e<<16)|mt;
      run += tl<<7;
    }
    *ntiles = nt;
  }
}

__global__ __launch_bounds__(256) void scatter_k(const int2* __restrict__ tidx, const float2* __restrict__ tw,
                                                 int* __restrict__ pcur, int* __restrict__ meta,
                                                 float* __restrict__ pw){
  int t = blockIdx.x*256 + threadIdx.x;
  if (t >= 4096) return;
  int2 ii = tidx[t]; float2 ww = tw[t];
  int p0 = atomicAdd(&pcur[ii.x],1); meta[p0] = t*2;   pw[p0] = ww.x;
  int p1 = atomicAdd(&pcur[ii.y],1); meta[p1] = t*2+1; pw[p1] = ww.y;
}

// ------------------------------ MoE GEMMs v5: R0 m97 template + BN=256 + B-locality grid ------------------------------
// Evidence R0-R4: staging supply scales with blocks/CU (10.7 TB/s @2-3 blk/CU vs 4.8 @1), not with
// pipeline depth. So: 256 threads, SINGLE-buffer 24KB LDS (A 128x32 + B 256x32 -> 2-3 blocks/CU),
// m97 2-syncthreads loop, compiler-scheduled interior. Intensity 85 FLOP/B (vs R0's 64).
// BK=32 swizzle (R4-verified, 0 conflicts): stage src chunk cs = cl ^ ((row>>1)&3), read chunk
// ch = quad ^ ((lrow>>1)&3); LDS stays linear (both-sides involution).
// Grid: blockIdx.x = row-tile (fast), blockIdx.y = col-panel (slow) -> consecutively-dispatched
// blocks share the B panel AND (expert-sorted tileinfo) the expert -> per-XCD L2 reuse of B.

// up: BN=256 virtual (128 real cols each of w1,w3 interleaved per 16). bx: 22 panels.
__global__ __launch_bounds__(256) void moe_up_p(const u16* __restrict__ hn_bf,
        const u16* __restrict__ w1t, const u16* __restrict__ w3t,
        const int* __restrict__ meta, const int* __restrict__ poff, const int* __restrict__ pcnt,
        const int* __restrict__ tileinfo, const int* __restrict__ ntiles,
        u16* __restrict__ g_pool){
  const int y = blockIdx.x;
  if (y >= *ntiles) return;
  const int bx = blockIdx.y;
  const int ti = tileinfo[y];
  const int e = ti>>16, mt = ti & 0xffff;
  const int base = poff[e], cnt = pcnt[e];
  __shared__ u16 lds[12288];            // A 128x32 (4096 u16) + B 256x32 (8192 u16) = 24 KB
  const int t = threadIdx.x;
  const int w = t>>6, lane = t&63, lrow = lane&15, quad = lane>>4;
  // staging: slot t covers row t>>2, dest chunk t&3; src chunk swizzled (row>>1)&3 invariant mod 64
  const int r0 = t>>2, cl = t&3;
  const int cs = cl ^ ((r0>>1)&3);
  int ra0 = mt*128 + r0, ra1 = ra0 + 64;
  int tok0 = (ra0 < cnt) ? (meta[base+ra0]>>1) : 0;
  int tok1 = (ra1 < cnt) ? (meta[base+ra1]>>1) : 0;
  const u16* pA0 = hn_bf + (size_t)tok0*1024 + cs*8;
  const u16* pA1 = hn_bf + (size_t)tok1*1024 + cs*8;
  // B virtual rows r0+g*64: mat=(v>>4)&1, col = bx*128 + ((v>>5)<<4) + (v&15)
  int v0 = r0,       c0v = bx*128 + ((v0>>5)<<4) + (v0&15);
  int v1 = r0 + 64,  c1v = bx*128 + ((v1>>5)<<4) + (v1&15);
  int v2 = r0 + 128, c2v = bx*128 + ((v2>>5)<<4) + (v2&15);
  int v3 = r0 + 192, c3v = bx*128 + ((v3>>5)<<4) + (v3&15);
  const u16* pB0 = (((v0>>4)&1) ? w3t : w1t) + ((size_t)e*2816 + c0v)*1024 + cs*8;
  const u16* pB1 = (((v1>>4)&1) ? w3t : w1t) + ((size_t)e*2816 + c1v)*1024 + cs*8;
  const u16* pB2 = (((v2>>4)&1) ? w3t : w1t) + ((size_t)e*2816 + c2v)*1024 + cs*8;
  const u16* pB3 = (((v3>>4)&1) ? w3t : w1t) + ((size_t)e*2816 + c3v)*1024 + cs*8;
  floatx4 acc[8][4];
  #pragma unroll
  for (int i=0;i<8;++i)
  #pragma unroll
  for (int jn=0;jn<4;++jn) acc[i][jn] = floatx4{0.f,0.f,0.f,0.f};
  const int ch = quad ^ ((lrow>>1)&3);
  const int aoff = lrow*32 + ch*8;                    // + mi*512
  const int boff = 4096 + (w*64 + lrow)*32 + ch*8;    // + ni*512
  u16* dA = lds + w*512;                // wave-uniform LDS dests (u16)
  u16* dB = lds + 4096 + w*512;
  for (int k0=0; k0<1024; k0+=32){
    __syncthreads();
    gl16(pA0, dA); gl16(pA1, dA+2048);
    gl16(pB0, dB); gl16(pB1, dB+2048); gl16(pB2, dB+4096); gl16(pB3, dB+6144);
    pA0+=32; pA1+=32; pB0+=32; pB1+=32; pB2+=32; pB3+=32;
    __syncthreads();
    bf16x8 bfr[4];
    #pragma unroll
    for (int ni=0;ni<4;++ni) bfr[ni] = *(const bf16x8*)&lds[boff + ni*512];
    #pragma unroll
    for (int mi=0;mi<8;++mi){
      bf16x8 af = *(const bf16x8*)&lds[aoff + mi*512];
      #pragma unroll
      for (int ni=0;ni<4;++ni) acc[mi][ni] = mfma16(af, bfr[ni], acc[mi][ni]);
    }
  }
  #pragma unroll
  for (int mi=0;mi<8;++mi)
  #pragma unroll
  for (int p=0;p<2;++p)
  #pragma unroll
  for (int i=0;i<4;++i){
    int rit = mi*16 + quad*4 + i;
    if (mt*128 + rit < cnt){
      int prow = base + mt*128 + rit;
      int col = bx*128 + w*32 + p*16 + lrow;
      float x1 = acc[mi][2*p][i], x3 = acc[mi][2*p+1][i];
      float g = (x1 / (1.0f + expf(-x1))) * x3;
      g_pool[(size_t)prow*2816 + col] = f2bf(g);
    }
  }
}

// down: BM=128, BN=256 real, K=2816. bx: 4 panels of 256 out-cols.
__global__ __launch_bounds__(256) void moe_down_p(const u16* __restrict__ g_pool, const u16* __restrict__ w2t,
        const int* __restrict__ meta, const float* __restrict__ pw,
        const int* __restrict__ poff, const int* __restrict__ pcnt,
        const int* __restrict__ tileinfo, const int* __restrict__ ntiles,
        float* __restrict__ out_slot){
  const int y = blockIdx.x;
  if (y >= *ntiles) return;
  const int bx = blockIdx.y;
  const int ti = tileinfo[y];
  const int e = ti>>16, mt = ti & 0xffff;
  const int base = poff[e], cnt = pcnt[e];
  __shared__ u16 lds[12288];
  const int t = threadIdx.x;
  const int w = t>>6, lane = t&63, lrow = lane&15, quad = lane>>4;
  const int r0 = t>>2, cl = t&3;
  const int cs = cl ^ ((r0>>1)&3);
  const u16* pA0 = g_pool + (size_t)(base + mt*128 + r0)*2816 + cs*8;
  const u16* pA1 = g_pool + (size_t)(base + mt*128 + r0 + 64)*2816 + cs*8;
  const u16* pB0 = w2t + ((size_t)e*1024 + bx*256 + r0)*2816 + cs*8;
  const u16* pB1 = pB0 + (size_t)64*2816;
  const u16* pB2 = pB0 + (size_t)128*2816;
  const u16* pB3 = pB0 + (size_t)192*2816;
  floatx4 acc[8][4];
  #pragma unroll
  for (int i=0;i<8;++i)
  #pragma unroll
  for (int jn=0;jn<4;++jn) acc[i][jn] = floatx4{0.f,0.f,0.f,0.f};
  const int ch = quad ^ ((lrow>>1)&3);
  const int aoff = lrow*32 + ch*8;
  const int boff = 4096 + (w*64 + lrow)*32 + ch*8;
  u16* dA = lds + w*512;
  u16* dB = lds + 4096 + w*512;
  for (int k0=0; k0<2816; k0+=32){
    __syncthreads();
    gl16(pA0, dA); gl16(pA1, dA+2048);
    gl16(pB0, dB); gl16(pB1, dB+2048); gl16(pB2, dB+4096); gl16(pB3, dB+6144);
    pA0+=32; pA1+=32; pB0+=32; pB1+=32; pB2+=32; pB3+=32;
    __syncthreads();
    bf16x8 bfr[4];
    #pragma unroll
    for (int ni=0;ni<4;++ni) bfr[ni] = *(const bf16x8*)&lds[boff + ni*512];
    #pragma unroll
    for (int mi=0;mi<8;++mi){
      bf16x8 af = *(const bf16x8*)&lds[aoff + mi*512];
      #pragma unroll
      for (int ni=0;ni<4;++ni) acc[mi][ni] = mfma16(af, bfr[ni], acc[mi][ni]);
    }
  }
  #pragma unroll
  for (int mi=0;mi<8;++mi)
  #pragma unroll
  for (int ni=0;ni<4;++ni)
  #pragma unroll
  for (int i=0;i<4;++i){
    int ml = mt*128 + mi*16 + quad*4 + i;
    if (ml < cnt){
      int mm = meta[base+ml];
      int token = mm>>1, slot = mm&1;
      float wgt = pw[base+ml];
      int col = bx*256 + w*64 + ni*16 + lrow;
      out_slot[(size_t)slot*4194304 + (size_t)token*1024 + col] = wgt*acc[mi][ni][i];
    }
  }
}

// ------------------------------ launcher ------------------------------
extern "C" void kernel_launch(void* const* d_in, const int* in_sizes, int n_in,
                              void* d_out, int out_size, void* d_ws, size_t ws_size,
                              hipStream_t stream){
  const float* x    = (const float*)d_in[0];
  const float* fcos = (const float*)d_in[3];
  const float* fsin = (const float*)d_in[4];
  const float* anw  = (const float*)d_in[5];
  const float* fnw  = (const float*)d_in[6];
  const float* wq   = (const float*)d_in[7];
  const float* wk   = (const float*)d_in[8];
  const float* wv_  = (const float*)d_in[9];
  const float* wo   = (const float*)d_in[10];
  const float* gw   = (const float*)d_in[11];
  const float* w1e  = (const float*)d_in[12];
  const float* w2e  = (const float*)d_in[13];
  const float* w3e  = (const float*)d_in[14];
  float* out = (float*)d_out;

  char* ws = (char*)d_ws;
  size_t off = 0;
  auto alloc = [&](size_t b)->void*{ void* p = ws + off; off += (b + 255) & ~(size_t)255; return p; };

  u16* wqkv_t = (u16*)alloc(3145728);     // [1536][1024] bf16 (wq^T | wk^T | wv^T)
  u16* wo_t   = (u16*)alloc(2097152);     // [1024][1024]
  u16* w1t    = (u16*)alloc(46137344);    // [8][2816][1024]
  u16* w3t    = (u16*)alloc(46137344);
  u16* w2t    = (u16*)alloc(46137344);    // [8][1024][2816]
  u16* xn_b   = (u16*)alloc(8388608);
  float* qkv_f= (float*)alloc(25165824);  // [4096][1536]  (reused as out_slot after attention)
  u16* q_b    = (u16*)alloc(8388608);     // (second half of out_slot reuse)
  u16* k_b    = (u16*)alloc(2097152);
  u16* v_b    = (u16*)alloc(2097152);
  u16* at_b   = (u16*)alloc(8388608);
  float* h_f  = (float*)alloc(16777216);
  u16* hn_b   = (u16*)alloc(8388608);
  int2* tidx  = (int2*)alloc(32768);
  float2* tw  = (float2*)alloc(32768);
  int* pcnt   = (int*)alloc(256);
  int* poff   = (int*)alloc(256);
  int* pcur   = (int*)alloc(256);
  int* tinfo  = (int*)alloc(512);
  int* ntl    = (int*)alloc(256);
  int* meta   = (int*)alloc(40960);       // 9344+ slots
  float* pw   = (float*)alloc(40960);
  u16* g_pool = (u16*)alloc(57671680);

  float* out_slot = (float*)qkv_f;        // 32 MB: qkv_f (24 MB) + q_b (8 MB), both dead post-attention

  // all weight transpose-casts in one launch
  tcast_all<<<17536, 256, 0, stream>>>(wq, wk, wv_, wo, w1e, w3e, w2e,
                                       wqkv_t, wo_t, w1t, w3t, w2t);

  // attention input norm
  rmsnorm_k<<<4096, 256, 0, stream>>>(x, anw, xn_b);

  // fused QKV projection: [4096,1024] x [1536,1024]^T -> fp32 [4096][1536]
  gemm128<0><<<dim3(12,32), 256, 0, stream>>>(xn_b, wqkv_t, 4096, 1536, 1024, qkv_f, nullptr);

  // RoPE q,k + cast v + pcnt init, one launch
  rope_vcast_k<<<10752, 256, 0, stream>>>(qkv_f, q_b, k_b, v_b, fcos, fsin, pcnt);

  // flash attention (paired q-tiles, uniform load)
  attn2_k<<<dim3(8,16,4), 256, 0, stream>>>(q_b, k_b, v_b, at_b);

  // output projection + residual -> h
  gemm128<1><<<dim3(8,32), 256, 0, stream>>>(at_b, wo_t, 4096, 1024, 1024, h_f, x);

  // ffn norm (bf16 for experts)
  rmsnorm_k<<<4096, 256, 0, stream>>>(h_f, fnw, hn_b);

  // routing (128-row tiles)
  gate_top2<<<1024, 256, 0, stream>>>(h_f, fnw, gw, tidx, tw, pcnt);
  offsets_k<<<1, 64, 0, stream>>>(pcnt, poff, pcur, tinfo, ntl);
  scatter_k<<<16, 256, 0, stream>>>(tidx, tw, pcur, meta, pw);

  // expert GEMMs (m97 template, BN=256, B-locality grid: x=row-tile fast, y=col-panel slow)
  moe_up_p<<<dim3(72,22), 256, 0, stream>>>(hn_b, w1t, w3t, meta, poff, pcnt, tinfo, ntl, g_pool);
  moe_down_p<<<dim3(72,4), 256, 0, stream>>>(g_pool, w2t, meta, pw, poff, pcnt, tinfo, ntl, out_slot);

  // final residual add: out = h + slot0 + slot1
  final_add<<<4096, 256, 0, stream>>>(h_f, out_slot, out_slot + 4194304, out, 1048576);
}

// Round 6
// 873.366 us; speedup vs baseline: 1.2721x; 1.2721x over previous
//
#include <hip/hip_runtime.h>
#include <hip/hip_bf16.h>

typedef unsigned short u16;
typedef __attribute__((ext_vector_type(8))) __bf16 bf16x8;
typedef __attribute__((ext_vector_type(4))) float floatx4;

__device__ __forceinline__ u16 f2bf(float f){
  union { float f; unsigned u; } v; v.f = f;
  unsigned u = v.u;
  return (u16)((u + 0x7fffu + ((u >> 16) & 1u)) >> 16);
}

__device__ __forceinline__ floatx4 mfma16(bf16x8 a, bf16x8 b, floatx4 c){
  return __builtin_amdgcn_mfma_f32_16x16x32_bf16(a, b, c, 0, 0, 0);
}

// async global->LDS, 16B per lane. LDS dest = wave-uniform base + lane*16.
__device__ __forceinline__ void gl16(const u16* g, u16* l){
  __builtin_amdgcn_global_load_lds((const __attribute__((address_space(1))) unsigned int*)g,
                                   (__attribute__((address_space(3))) unsigned int*)l, 16, 0, 0);
}

// ------------------------------ fused transpose-cast: all 7 weights in one launch ------------------------------
__global__ __launch_bounds__(256) void tcast_all(
    const float* __restrict__ wq, const float* __restrict__ wk,
    const float* __restrict__ wv, const float* __restrict__ wo,
    const float* __restrict__ w1e, const float* __restrict__ w3e, const float* __restrict__ w2e,
    u16* __restrict__ wqkv_t, u16* __restrict__ wo_t,
    u16* __restrict__ w1t, u16* __restrict__ w3t, u16* __restrict__ w2t){
  int bid = blockIdx.x;
  const float* src; u16* dst; int R, C, nbx;
  if (bid < 256)        { src=wq;  dst=wqkv_t;          R=1024; C=1024; nbx=16; }
  else if (bid < 320)   { src=wk;  dst=wqkv_t+1048576;  R=1024; C=256;  nbx=4;  bid-=256; }
  else if (bid < 384)   { src=wv;  dst=wqkv_t+1310720;  R=1024; C=256;  nbx=4;  bid-=320; }
  else if (bid < 640)   { src=wo;  dst=wo_t;            R=1024; C=1024; nbx=16; bid-=384; }
  else if (bid < 6272)  { src=w1e; dst=w1t;             R=1024; C=2816; nbx=44; bid-=640; }
  else if (bid < 11904) { src=w3e; dst=w3t;             R=1024; C=2816; nbx=44; bid-=6272; }
  else                  { src=w2e; dst=w2t;             R=2816; C=1024; nbx=16; bid-=11904; }
  const int per = nbx * (R>>6);
  const int z = bid / per; int rem = bid - z*per;
  const int by = rem / nbx, bx = rem - by*nbx;
  src += (size_t)z * R * C;
  dst += (size_t)z * R * C;
  __shared__ u16 tile[64][65];
  const int r0 = by*64, c0 = bx*64;
  const int t = threadIdx.x;
  const int tr = t>>4, tc = (t&15)*4;
  #pragma unroll
  for (int i=0;i<4;++i){
    float4 v = *(const float4*)(src + (size_t)(r0+tr+i*16)*C + c0 + tc);
    tile[tr+i*16][tc]   = f2bf(v.x);
    tile[tr+i*16][tc+1] = f2bf(v.y);
    tile[tr+i*16][tc+2] = f2bf(v.z);
    tile[tr+i*16][tc+3] = f2bf(v.w);
  }
  __syncthreads();
  const int on = t>>3, ok = (t&7)*8;
  #pragma unroll
  for (int p=0;p<2;++p){
    int n = on + p*32;
    ushort u[8];
    #pragma unroll
    for (int j=0;j<8;++j) u[j] = tile[ok+j][n];
    *(uint4*)(dst + (size_t)(c0+n)*R + r0 + ok) = *(uint4*)u;
  }
}

// ------------------------------ elementwise ------------------------------
__global__ __launch_bounds__(256) void rmsnorm_k(const float* __restrict__ x, const float* __restrict__ w,
                                                 u16* __restrict__ ob){
  const int row = blockIdx.x, t = threadIdx.x;
  float4 v = ((const float4*)(x + (size_t)row*1024))[t];
  float ss = v.x*v.x + v.y*v.y + v.z*v.z + v.w*v.w;
  #pragma unroll
  for (int o=32;o>0;o>>=1) ss += __shfl_down(ss, o);
  __shared__ float red[4];
  if ((t&63)==0) red[t>>6]=ss;
  __syncthreads();
  float sc = rsqrtf((red[0]+red[1]+red[2]+red[3])*(1.0f/1024.0f) + 1e-5f);
  float4 wv = ((const float4*)w)[t];
  ushort4 q; q.x=f2bf(v.x*sc*wv.x); q.y=f2bf(v.y*sc*wv.y); q.z=f2bf(v.z*sc*wv.z); q.w=f2bf(v.w*sc*wv.w);
  ((ushort4*)(ob + (size_t)row*1024))[t] = q;
}

// fused: rope(q) | rope(k) | cast(v), plus pcnt zero-init.
__global__ __launch_bounds__(256) void rope_vcast_k(const float* __restrict__ qkv,
      u16* __restrict__ q_b, u16* __restrict__ k_b, u16* __restrict__ v_b,
      const float* __restrict__ cosb, const float* __restrict__ sinb, int* __restrict__ pcnt){
  int gid = blockIdx.x*256 + threadIdx.x;
  if (gid < 8) pcnt[gid] = 0;
  if (gid < 2097152){
    int idx = gid;
    int i = idx & 31, rest = idx >> 5;
    int h = rest & 15, bs = rest >> 4;
    int s = bs & 1023;
    const float* sp = qkv + (size_t)bs*1536 + h*64 + 2*i;
    float a = sp[0], b = sp[1];
    float c = cosb[s*32+i], sn = sinb[s*32+i];
    size_t p = (((size_t)bs*16) + h)*64 + 2*i;
    q_b[p]   = f2bf(a*c - b*sn);
    q_b[p+1] = f2bf(a*sn + b*c);
  } else if (gid < 2621440){
    int idx = gid - 2097152;
    int i = idx & 31, rest = idx >> 5;
    int h = rest & 3, bs = rest >> 2;
    int s = bs & 1023;
    const float* sp = qkv + (size_t)bs*1536 + 1024 + h*64 + 2*i;
    float a = sp[0], b = sp[1];
    float c = cosb[s*32+i], sn = sinb[s*32+i];
    size_t p = (((size_t)bs*4) + h)*64 + 2*i;
    k_b[p]   = f2bf(a*c - b*sn);
    k_b[p+1] = f2bf(a*sn + b*c);
  } else {
    int idx = gid - 2621440;  // < 131072
    int row = idx >> 5, c8 = (idx & 31)*8;
    const float* s = qkv + (size_t)row*1536 + 1280 + c8;
    float4 v0 = *(const float4*)s, v1 = *(const float4*)(s+4);
    ushort u[8] = {f2bf(v0.x),f2bf(v0.y),f2bf(v0.z),f2bf(v0.w),f2bf(v1.x),f2bf(v1.y),f2bf(v1.z),f2bf(v1.w)};
    *(uint4*)(v_b + (size_t)row*256 + c8) = *(uint4*)u;
  }
}

__global__ __launch_bounds__(256) void final_add(const float* __restrict__ h, const float* __restrict__ s0,
                                                 const float* __restrict__ s1, float* __restrict__ out, int n4){
  int i = blockIdx.x*256 + threadIdx.x;
  if (i >= n4) return;
  float4 a = ((const float4*)h)[i], b = ((const float4*)s0)[i], c = ((const float4*)s1)[i];
  float4 o; o.x=a.x+b.x+c.x; o.y=a.y+b.y+c.y; o.z=a.z+b.z+c.z; o.w=a.w+b.w+c.w;
  ((float4*)out)[i] = o;
}

// ------------------------------ m97-style 128x128 GEMM (qkv / wo projections) ------------------------------
template<int EPI>
__global__ __launch_bounds__(256) void gemm128(const u16* __restrict__ A, const u16* __restrict__ Bt,
                                               int M, int N, int K,
                                               float* __restrict__ Cf, const float* __restrict__ resid){
  __shared__ u16 As[128*32];
  __shared__ u16 Bs[128*32];
  const int t = threadIdx.x;
  const int wave = t>>6, lane = t&63, lrow = lane&15, quad = lane>>4;
  const int wm = (wave&1)*64, wn = (wave>>1)*64;
  const int mbase = blockIdx.y*128, nbase = blockIdx.x*128;
  const int ca = wave*128 + lane;
  const int r0 = ca>>2;
  const int jsw = (ca&3) ^ ((r0 + (r0>>2))&3);
  const u16* a0 = A  + (size_t)(mbase + r0)*K + jsw*8;
  const u16* a1 = a0 + (size_t)16*K;
  const u16* b0 = Bt + (size_t)(nbase + r0)*K + jsw*8;
  const u16* b1 = b0 + (size_t)16*K;
  u16* lA = As + wave*1024;
  u16* lB = Bs + wave*1024;
  const int swz = (lrow + (lrow>>2)) & 3;
  floatx4 acc[4][4];
  #pragma unroll
  for (int i=0;i<4;++i)
  #pragma unroll
  for (int j=0;j<4;++j) acc[i][j] = floatx4{0.f,0.f,0.f,0.f};
  for (int k0=0;k0<K;k0+=32){
    __syncthreads();
    gl16(a0, lA); gl16(a1, lA+512);
    gl16(b0, lB); gl16(b1, lB+512);
    a0 += 32; a1 += 32; b0 += 32; b1 += 32;
    __syncthreads();
    bf16x8 af[4], bfr[4];
    #pragma unroll
    for (int mi=0;mi<4;++mi) af[mi]  = *(const bf16x8*)&As[(((wm+mi*16+lrow)<<2) + (quad^swz))*8];
    #pragma unroll
    for (int ni=0;ni<4;++ni) bfr[ni] = *(const bf16x8*)&Bs[(((wn+ni*16+lrow)<<2) + (quad^swz))*8];
    #pragma unroll
    for (int mi=0;mi<4;++mi)
    #pragma unroll
    for (int ni=0;ni<4;++ni) acc[mi][ni] = mfma16(af[mi], bfr[ni], acc[mi][ni]);
  }
  #pragma unroll
  for (int mi=0;mi<4;++mi)
  #pragma unroll
  for (int ni=0;ni<4;++ni)
  #pragma unroll
  for (int i=0;i<4;++i){
    int row = mbase + wm + mi*16 + quad*4 + i;
    int col = nbase + wn + ni*16 + lrow;
    float val = acc[mi][ni][i];
    if (EPI==1) val += resid[(size_t)row*N + col];
    Cf[(size_t)row*N + col] = val;
  }
}

// ------------------------------ flash attention, paired q-tiles ------------------------------
#define ATS 72

__device__ __forceinline__ void qk_softmax(int kt, int qt, const u16* Qs, const u16* Ks, u16* Ps,
                                           floatx4* out, float* m_i, float* l_i,
                                           int wv, int lrow, int quad){
  const float NEG_INF = -__builtin_inff();
  floatx4 sc[4];
  #pragma unroll
  for (int i=0;i<4;++i) sc[i] = floatx4{0.f,0.f,0.f,0.f};
  #pragma unroll
  for (int ks=0; ks<2; ++ks){
    bf16x8 af = *(const bf16x8*)&Qs[(wv*16+lrow)*ATS + ks*32 + quad*8];
    #pragma unroll
    for (int nt=0;nt<4;++nt){
      bf16x8 bf = *(const bf16x8*)&Ks[(nt*16+lrow)*ATS + ks*32 + quad*8];
      sc[nt] = mfma16(af, bf, sc[nt]);
    }
  }
  const bool diag = (kt==qt);
  float rmax[4] = {NEG_INF,NEG_INF,NEG_INF,NEG_INF};
  #pragma unroll
  for (int nt=0;nt<4;++nt)
  #pragma unroll
  for (int i=0;i<4;++i){
    float s = sc[nt][i]*0.125f;
    if (diag && (nt*16+lrow > wv*16 + quad*4 + i)) s = NEG_INF;
    sc[nt][i] = s;
    rmax[i] = fmaxf(rmax[i], s);
  }
  #pragma unroll
  for (int o=1;o<16;o<<=1)
    #pragma unroll
    for (int i=0;i<4;++i) rmax[i] = fmaxf(rmax[i], __shfl_xor(rmax[i], o));
  float al[4], psum[4] = {0.f,0.f,0.f,0.f};
  #pragma unroll
  for (int i=0;i<4;++i){
    float mn = fmaxf(m_i[i], rmax[i]);
    al[i] = expf(m_i[i]-mn);
    m_i[i] = mn;
  }
  #pragma unroll
  for (int nt=0;nt<4;++nt)
  #pragma unroll
  for (int i=0;i<4;++i){
    float p = expf(sc[nt][i]-m_i[i]);
    sc[nt][i] = p;
    psum[i] += p;
  }
  #pragma unroll
  for (int o=1;o<16;o<<=1)
    #pragma unroll
    for (int i=0;i<4;++i) psum[i] += __shfl_xor(psum[i], o);
  #pragma unroll
  for (int i=0;i<4;++i) l_i[i] = l_i[i]*al[i] + psum[i];
  #pragma unroll
  for (int nt=0;nt<4;++nt)
    #pragma unroll
    for (int i=0;i<4;++i) out[nt][i] *= al[i];
  u16* Pw = Ps + wv*16*ATS;
  #pragma unroll
  for (int nt=0;nt<4;++nt)
  #pragma unroll
  for (int i=0;i<4;++i)
    Pw[(quad*4+i)*ATS + nt*16 + lrow] = f2bf(sc[nt][i]);
}

__device__ __forceinline__ void pv_acc(const u16* Ps, const u16* Vt, floatx4* out,
                                       int wv, int lrow, int quad){
  const u16* Pw = Ps + wv*16*ATS;
  #pragma unroll
  for (int ks=0; ks<2; ++ks){
    bf16x8 af = *(const bf16x8*)&Pw[lrow*ATS + ks*32 + quad*8];
    #pragma unroll
    for (int nt=0;nt<4;++nt){
      bf16x8 bf = *(const bf16x8*)&Vt[(nt*16+lrow)*ATS + ks*32 + quad*8];
      out[nt] = mfma16(af, bf, out[nt]);
    }
  }
}

__global__ __launch_bounds__(256) void attn2_k(const u16* __restrict__ qb, const u16* __restrict__ kb,
                                               const u16* __restrict__ vb, u16* __restrict__ ob){
  const int bx = blockIdx.x, h = blockIdx.y, b = blockIdx.z;
  const int qtA = bx, qtB = 15 - bx;
  const int kvh = h >> 2;
  __shared__ u16 QsA[64*ATS], QsB[64*ATS], Ks[64*ATS], Vt[64*ATS], PsA[64*ATS], PsB[64*ATS];
  const int t = threadIdx.x;
  const int wv = t>>6, lane = t&63, lrow = lane&15, quad = lane>>4;
  const float NEG_INF = -__builtin_inff();
  {
    const int r = t>>2, c0 = (t&3)*16;
    const u16* sA = qb + ((((size_t)(b*1024 + qtA*64 + r))*16) + h)*64 + c0;
    *(uint4*)(&QsA[r*ATS + c0])     = *(const uint4*)(sA);
    *(uint4*)(&QsA[r*ATS + c0 + 8]) = *(const uint4*)(sA + 8);
    const u16* sB = qb + ((((size_t)(b*1024 + qtB*64 + r))*16) + h)*64 + c0;
    *(uint4*)(&QsB[r*ATS + c0])     = *(const uint4*)(sB);
    *(uint4*)(&QsB[r*ATS + c0 + 8]) = *(const uint4*)(sB + 8);
  }
  floatx4 outA[4], outB[4];
  float mA[4], lA[4], mB[4], lB[4];
  #pragma unroll
  for (int i=0;i<4;++i){
    outA[i] = floatx4{0.f,0.f,0.f,0.f}; outB[i] = floatx4{0.f,0.f,0.f,0.f};
    mA[i]=NEG_INF; lA[i]=0.f; mB[i]=NEG_INF; lB[i]=0.f;
  }
  for (int kt=0; kt<=qtB; ++kt){
    const int k0 = kt*64;
    __syncthreads();
    {
      const int r = t>>2, c0 = (t&3)*16;
      const u16* src = kb + ((((size_t)(b*1024 + k0 + r))*4) + kvh)*64 + c0;
      *(uint4*)(&Ks[r*ATS + c0])     = *(const uint4*)(src);
      *(uint4*)(&Ks[r*ATS + c0 + 8]) = *(const uint4*)(src + 8);
    }
    {
      const int r = t>>3, m = t&7, c0 = m*8;
      #pragma unroll
      for (int half=0; half<2; ++half){
        int rr = r + half*32;
        uint4 v = *(const uint4*)(vb + ((((size_t)(b*1024 + k0 + rr))*4) + kvh)*64 + c0);
        const u16* s = (const u16*)&v;
        #pragma unroll
        for (int j=0;j<8;++j){
          int jj = (j + m) & 7;
          Vt[(c0+jj)*ATS + rr] = s[jj];
        }
      }
    }
    __syncthreads();
    const bool doA = (kt <= qtA);
    if (doA) qk_softmax(kt, qtA, QsA, Ks, PsA, outA, mA, lA, wv, lrow, quad);
    qk_softmax(kt, qtB, QsB, Ks, PsB, outB, mB, lB, wv, lrow, quad);
    __syncthreads();
    if (doA) pv_acc(PsA, Vt, outA, wv, lrow, quad);
    pv_acc(PsB, Vt, outB, wv, lrow, quad);
  }
  #pragma unroll
  for (int nt=0;nt<4;++nt)
  #pragma unroll
  for (int i=0;i<4;++i){
    int rA = qtA*64 + wv*16 + quad*4 + i;
    int rB = qtB*64 + wv*16 + quad*4 + i;
    ob[((size_t)(b*1024 + rA))*1024 + h*64 + nt*16 + lrow] = f2bf(outA[nt][i] / lA[i]);
    ob[((size_t)(b*1024 + rB))*1024 + h*64 + nt*16 + lrow] = f2bf(outB[nt][i] / lB[i]);
  }
}

// ------------------------------ MoE routing (128-row tiles) ------------------------------
__global__ __launch_bounds__(256) void gate_top2(const float* __restrict__ h, const float* __restrict__ fnw,
                                                 const float* __restrict__ gw,
                                                 int2* __restrict__ tidx, float2* __restrict__ tw,
                                                 int* __restrict__ counts){
  const int token = blockIdx.x*4 + (threadIdx.x>>6);
  const int lane = threadIdx.x & 63;
  const float* xr = h + (size_t)token*1024;
  float ss = 0.f;
  float acc[8] = {0,0,0,0,0,0,0,0};
  for (int it=0; it<16; ++it){
    int d = lane + it*64;
    float xv = xr[d];
    ss += xv*xv;
    float xw = xv * fnw[d];
    const float4* g4 = (const float4*)(gw + d*8);
    float4 g0 = g4[0], g1 = g4[1];
    acc[0] += xw*g0.x; acc[1] += xw*g0.y; acc[2] += xw*g0.z; acc[3] += xw*g0.w;
    acc[4] += xw*g1.x; acc[5] += xw*g1.y; acc[6] += xw*g1.z; acc[7] += xw*g1.w;
  }
  #pragma unroll
  for (int o=1;o<64;o<<=1){
    ss += __shfl_xor(ss, o);
    #pragma unroll
    for (int e=0;e<8;++e) acc[e] += __shfl_xor(acc[e], o);
  }
  if (lane==0){
    int i0=0; float v0=acc[0];
    #pragma unroll
    for (int e=1;e<8;++e) if (acc[e] > v0){ v0=acc[e]; i0=e; }
    int i1=-1; float v1=-__builtin_inff();
    #pragma unroll
    for (int e=0;e<8;++e) if (e!=i0 && acc[e] > v1){ v1=acc[e]; i1=e; }
    float scl = rsqrtf(ss*(1.0f/1024.0f) + 1e-5f);
    float e2 = expf((v1 - v0)*scl);
    float w0 = 1.0f/(1.0f+e2);
    float w1 = e2/(1.0f+e2);
    int2 ii; ii.x=i0; ii.y=i1; tidx[token]=ii;
    float2 ww; ww.x=w0; ww.y=w1; tw[token]=ww;
    atomicAdd(&counts[i0],1);
    atomicAdd(&counts[i1],1);
  }
}

__global__ void offsets_k(const int* __restrict__ counts, int* __restrict__ poff, int* __restrict__ pcur,
                          int* __restrict__ tileinfo, int* __restrict__ ntiles){
  if (threadIdx.x==0){
    int run=0, nt=0;
    for (int e=0;e<8;++e){
      poff[e]=run; pcur[e]=run;
      int c = counts[e];
      int tl = (c+127)>>7;
      for (int mt=0; mt<tl; ++mt) tileinfo[nt++] = (e<<16)|mt;
      run += tl<<7;
    }
    *ntiles = nt;
  }
}

__global__ __launch_bounds__(256) void scatter_k(const int2* __restrict__ tidx, const float2* __restrict__ tw,
                                                 int* __restrict__ pcur, int* __restrict__ meta,
                                                 float* __restrict__ pw){
  int t = blockIdx.x*256 + threadIdx.x;
  if (t >= 4096) return;
  int2 ii = tidx[t]; float2 ww = tw[t];
  int p0 = atomicAdd(&pcur[ii.x],1); meta[p0] = t*2;   pw[p0] = ww.x;
  int p1 = atomicAdd(&pcur[ii.y],1); meta[p1] = t*2+1; pw[p1] = ww.y;
}

// ------------------------------ MoE GEMMs v6: m97 regime, 512 thr, BM=128 BN=256, 64-VGPR acc ------------------------------
// Five-round evidence: supply (~10.7 TB/s) requires >=2 blocks/CU with the m97 single-buffer loop;
// R5's regression = 164 VGPR (acc 128/thread) + row-fast grid. Fix: 512 threads keep acc at 64
// VGPR (acc[4][4], 8 waves 2Mx4N, 64x64 out each) while intensity rises to 85 FLOP/B.
// __launch_bounds__(512,4) pins VGPR<=128 -> 2 blocks/CU (LDS 24KB). Grid = R0's proven order:
// blockIdx.x = col-panel (fast, shares the A row-tile), blockIdx.y = row-tile.
// BK=32 both-sides swizzle (R4/R5-verified 0 conflicts): stage src chunk cs=cl^((row>>1)&3),
// read chunk ch=quad^((lrow>>1)&3), LDS linear.

// up: BN=256 virtual (128 real cols each of w1,w3, interleaved per 16). grid (22, 72).
__global__ __launch_bounds__(512, 4) void moe_up_p(const u16* __restrict__ hn_bf,
        const u16* __restrict__ w1t, const u16* __restrict__ w3t,
        const int* __restrict__ meta, const int* __restrict__ poff, const int* __restrict__ pcnt,
        const int* __restrict__ tileinfo, const int* __restrict__ ntiles,
        u16* __restrict__ g_pool){
  const int y = blockIdx.y;
  if (y >= *ntiles) return;
  const int bx = blockIdx.x;
  const int ti = tileinfo[y];
  const int e = ti>>16, mt = ti & 0xffff;
  const int base = poff[e], cnt = pcnt[e];
  __shared__ u16 lds[12288];            // A 128x32 (4096 u16) + B 256x32 (8192 u16) = 24 KB
  const int t = threadIdx.x;
  const int w = t>>6, lane = t&63, lrow = lane&15, quad = lane>>4;
  const int wm = w>>2, wn = w&3;        // 2M x 4N waves, 64x64 out each
  // staging: thread t covers A row r0 (one of 128) and B vrows r0, r0+128; dest chunk cl
  const int r0 = t>>2, cl = t&3;
  const int cs = cl ^ ((r0>>1)&3);      // swizzled source chunk ((v>>1)&3 invariant under +128)
  int ra = mt*128 + r0;
  int tok = (ra < cnt) ? (meta[base+ra]>>1) : 0;
  const u16* pA = hn_bf + (size_t)tok*1024 + cs*8;
  const int v1 = r0, v2 = r0 + 128;
  const int c1 = bx*128 + ((v1>>5)<<4) + (v1&15);
  const int c2 = bx*128 + ((v2>>5)<<4) + (v2&15);
  const u16* pB1 = (((v1>>4)&1) ? w3t : w1t) + ((size_t)e*2816 + c1)*1024 + cs*8;
  const u16* pB2 = (((v2>>4)&1) ? w3t : w1t) + ((size_t)e*2816 + c2)*1024 + cs*8;
  floatx4 acc[4][4];
  #pragma unroll
  for (int i=0;i<4;++i)
  #pragma unroll
  for (int jn=0;jn<4;++jn) acc[i][jn] = floatx4{0.f,0.f,0.f,0.f};
  const int ch = quad ^ ((lrow>>1)&3);
  const int aoff = wm*2048 + lrow*32 + ch*8;              // + mi*512
  const int boff = 4096 + (wn*64 + lrow)*32 + ch*8;       // + ni*512
  u16* dA  = lds + w*512;               // wave-uniform dests (u16), + lane*16B implicit
  u16* dB1 = lds + 4096 + w*512;
  u16* dB2 = lds + 8192 + w*512;
  for (int k0=0; k0<1024; k0+=32){
    __syncthreads();
    gl16(pA, dA); gl16(pB1, dB1); gl16(pB2, dB2);
    pA+=32; pB1+=32; pB2+=32;
    __syncthreads();
    bf16x8 bfr[4];
    #pragma unroll
    for (int ni=0;ni<4;++ni) bfr[ni] = *(const bf16x8*)&lds[boff + ni*512];
    #pragma unroll
    for (int mi=0;mi<4;++mi){
      bf16x8 af = *(const bf16x8*)&lds[aoff + mi*512];
      #pragma unroll
      for (int ni=0;ni<4;++ni) acc[mi][ni] = mfma16(af, bfr[ni], acc[mi][ni]);
    }
  }
  #pragma unroll
  for (int mi=0;mi<4;++mi)
  #pragma unroll
  for (int p=0;p<2;++p)
  #pragma unroll
  for (int i=0;i<4;++i){
    int rit = wm*64 + mi*16 + quad*4 + i;
    if (mt*128 + rit < cnt){
      int prow = base + mt*128 + rit;
      int col = bx*128 + (wn*2+p)*16 + lrow;
      float x1 = acc[mi][2*p][i], x3 = acc[mi][2*p+1][i];
      float g = (x1 / (1.0f + expf(-x1))) * x3;
      g_pool[(size_t)prow*2816 + col] = f2bf(g);
    }
  }
}

// down: BM=128, BN=256 real, K=2816. grid (4, 72).
__global__ __launch_bounds__(512, 4) void moe_down_p(const u16* __restrict__ g_pool, const u16* __restrict__ w2t,
        const int* __restrict__ meta, const float* __restrict__ pw,
        const int* __restrict__ poff, const int* __restrict__ pcnt,
        const int* __restrict__ tileinfo, const int* __restrict__ ntiles,
        float* __restrict__ out_slot){
  const int y = blockIdx.y;
  if (y >= *ntiles) return;
  const int bx = blockIdx.x;
  const int ti = tileinfo[y];
  const int e = ti>>16, mt = ti & 0xffff;
  const int base = poff[e], cnt = pcnt[e];
  __shared__ u16 lds[12288];
  const int t = threadIdx.x;
  const int w = t>>6, lane = t&63, lrow = lane&15, quad = lane>>4;
  const int wm = w>>2, wn = w&3;
  const int r0 = t>>2, cl = t&3;
  const int cs = cl ^ ((r0>>1)&3);
  const u16* pA  = g_pool + (size_t)(base + mt*128 + r0)*2816 + cs*8;
  const u16* pB1 = w2t + ((size_t)e*1024 + bx*256 + r0)*2816 + cs*8;
  const u16* pB2 = pB1 + (size_t)128*2816;
  floatx4 acc[4][4];
  #pragma unroll
  for (int i=0;i<4;++i)
  #pragma unroll
  for (int jn=0;jn<4;++jn) acc[i][jn] = floatx4{0.f,0.f,0.f,0.f};
  const int ch = quad ^ ((lrow>>1)&3);
  const int aoff = wm*2048 + lrow*32 + ch*8;
  const int boff = 4096 + (wn*64 + lrow)*32 + ch*8;
  u16* dA  = lds + w*512;
  u16* dB1 = lds + 4096 + w*512;
  u16* dB2 = lds + 8192 + w*512;
  for (int k0=0; k0<2816; k0+=32){
    __syncthreads();
    gl16(pA, dA); gl16(pB1, dB1); gl16(pB2, dB2);
    pA+=32; pB1+=32; pB2+=32;
    __syncthreads();
    bf16x8 bfr[4];
    #pragma unroll
    for (int ni=0;ni<4;++ni) bfr[ni] = *(const bf16x8*)&lds[boff + ni*512];
    #pragma unroll
    for (int mi=0;mi<4;++mi){
      bf16x8 af = *(const bf16x8*)&lds[aoff + mi*512];
      #pragma unroll
      for (int ni=0;ni<4;++ni) acc[mi][ni] = mfma16(af, bfr[ni], acc[mi][ni]);
    }
  }
  #pragma unroll
  for (int mi=0;mi<4;++mi)
  #pragma unroll
  for (int ni=0;ni<4;++ni)
  #pragma unroll
  for (int i=0;i<4;++i){
    int ml = mt*128 + wm*64 + mi*16 + quad*4 + i;
    if (ml < cnt){
      int mm = meta[base+ml];
      int token = mm>>1, slot = mm&1;
      float wgt = pw[base+ml];
      int col = bx*256 + wn*64 + ni*16 + lrow;
      out_slot[(size_t)slot*4194304 + (size_t)token*1024 + col] = wgt*acc[mi][ni][i];
    }
  }
}

// ------------------------------ launcher ------------------------------
extern "C" void kernel_launch(void* const* d_in, const int* in_sizes, int n_in,
                              void* d_out, int out_size, void* d_ws, size_t ws_size,
                              hipStream_t stream){
  const float* x    = (const float*)d_in[0];
  const float* fcos = (const float*)d_in[3];
  const float* fsin = (const float*)d_in[4];
  const float* anw  = (const float*)d_in[5];
  const float* fnw  = (const float*)d_in[6];
  const float* wq   = (const float*)d_in[7];
  const float* wk   = (const float*)d_in[8];
  const float* wv_  = (const float*)d_in[9];
  const float* wo   = (const float*)d_in[10];
  const float* gw   = (const float*)d_in[11];
  const float* w1e  = (const float*)d_in[12];
  const float* w2e  = (const float*)d_in[13];
  const float* w3e  = (const float*)d_in[14];
  float* out = (float*)d_out;

  char* ws = (char*)d_ws;
  size_t off = 0;
  auto alloc = [&](size_t b)->void*{ void* p = ws + off; off += (b + 255) & ~(size_t)255; return p; };

  u16* wqkv_t = (u16*)alloc(3145728);     // [1536][1024] bf16 (wq^T | wk^T | wv^T)
  u16* wo_t   = (u16*)alloc(2097152);     // [1024][1024]
  u16* w1t    = (u16*)alloc(46137344);    // [8][2816][1024]
  u16* w3t    = (u16*)alloc(46137344);
  u16* w2t    = (u16*)alloc(46137344);    // [8][1024][2816]
  u16* xn_b   = (u16*)alloc(8388608);
  float* qkv_f= (float*)alloc(25165824);  // [4096][1536]  (reused as out_slot after attention)
  u16* q_b    = (u16*)alloc(8388608);     // (second half of out_slot reuse)
  u16* k_b    = (u16*)alloc(2097152);
  u16* v_b    = (u16*)alloc(2097152);
  u16* at_b   = (u16*)alloc(8388608);
  float* h_f  = (float*)alloc(16777216);
  u16* hn_b   = (u16*)alloc(8388608);
  int2* tidx  = (int2*)alloc(32768);
  float2* tw  = (float2*)alloc(32768);
  int* pcnt   = (int*)alloc(256);
  int* poff   = (int*)alloc(256);
  int* pcur   = (int*)alloc(256);
  int* tinfo  = (int*)alloc(512);
  int* ntl    = (int*)alloc(256);
  int* meta   = (int*)alloc(40960);       // 9344+ slots
  float* pw   = (float*)alloc(40960);
  u16* g_pool = (u16*)alloc(57671680);

  float* out_slot = (float*)qkv_f;        // 32 MB: qkv_f (24 MB) + q_b (8 MB), both dead post-attention

  // all weight transpose-casts in one launch
  tcast_all<<<17536, 256, 0, stream>>>(wq, wk, wv_, wo, w1e, w3e, w2e,
                                       wqkv_t, wo_t, w1t, w3t, w2t);

  // attention input norm
  rmsnorm_k<<<4096, 256, 0, stream>>>(x, anw, xn_b);

  // fused QKV projection: [4096,1024] x [1536,1024]^T -> fp32 [4096][1536]
  gemm128<0><<<dim3(12,32), 256, 0, stream>>>(xn_b, wqkv_t, 4096, 1536, 1024, qkv_f, nullptr);

  // RoPE q,k + cast v + pcnt init, one launch
  rope_vcast_k<<<10752, 256, 0, stream>>>(qkv_f, q_b, k_b, v_b, fcos, fsin, pcnt);

  // flash attention (paired q-tiles, uniform load)
  attn2_k<<<dim3(8,16,4), 256, 0, stream>>>(q_b, k_b, v_b, at_b);

  // output projection + residual -> h
  gemm128<1><<<dim3(8,32), 256, 0, stream>>>(at_b, wo_t, 4096, 1024, 1024, h_f, x);

  // ffn norm (bf16 for experts)
  rmsnorm_k<<<4096, 256, 0, stream>>>(h_f, fnw, hn_b);

  // routing (128-row tiles)
  gate_top2<<<1024, 256, 0, stream>>>(h_f, fnw, gw, tidx, tw, pcnt);
  offsets_k<<<1, 64, 0, stream>>>(pcnt, poff, pcur, tinfo, ntl);
  scatter_k<<<16, 256, 0, stream>>>(tidx, tw, pcur, meta, pw);

  // expert GEMMs (512 thr, BM=128 BN=256, col-panel-fast grid)
  moe_up_p<<<dim3(22,72), 512, 0, stream>>>(hn_b, w1t, w3t, meta, poff, pcnt, tinfo, ntl, g_pool);
  moe_down_p<<<dim3(4,72), 512, 0, stream>>>(g_pool, w2t, meta, pw, poff, pcnt, tinfo, ntl, out_slot);

  // final residual add: out = h + slot0 + slot1
  final_add<<<4096, 256, 0, stream>>>(h_f, out_slot, out_slot + 4194304, out, 1048576);
}